// Round 8
// baseline (675.419 us; speedup 1.0000x reference)
//
#include <hip/hip_runtime.h>
#include <hip/hip_fp16.h>
#include <math.h>

#define WW 128
#define HH 128
#define DD 128
#define HW (WW * HH)
#define VOL (WW * HH * DD)
// padded (halo) geometry: 130^3, interior voxel (d,h,w) -> padded (d+1,h+1,w+1)
#define PW 130
#define PHW (130 * 130)
#define PVOL (130 * 130 * 130)
#define NSHELL 99848   // 130^3 - 128^3

typedef _Float16 f16x8 __attribute__((ext_vector_type(8)));
typedef _Float16 f16x4 __attribute__((ext_vector_type(4)));
typedef _Float16 f16x2 __attribute__((ext_vector_type(2)));
typedef float f32x4 __attribute__((ext_vector_type(4)));
typedef float f32x8v __attribute__((ext_vector_type(8)));
typedef float f32x16 __attribute__((ext_vector_type(16)));
typedef int int4v __attribute__((ext_vector_type(4)));
typedef int int2v __attribute__((ext_vector_type(2)));

__device__ __forceinline__ void stv(float* p, float v) { *p = v; }
__device__ __forceinline__ void stv(_Float16* p, float v) { *p = (_Float16)v; }

// Wb compact layout (56 B/voxel, lossless — rows 27..31 of the 32x32 C-tile
// are exact zeros and are dropped):
//   group g = vox>>5 (32 voxels), col = vox&31, group stride = 896 halfs.
//   chunk0 (half0 regs r=0..15, rows (r&3)+8*(r>>2)):  g*896 + col*16, 16 halfs
//   chunk1 (half1 regs r=0..11, rows (r&3)+8*(r>>2)+4): g*896 + 512 + col*12, 12 halfs
// tap m -> (h=(m>>2)&1, r=(m&3)+4*(m>>3)); h==0 -> chunk0[r], h==1 -> chunk1[r].

// ==========================================================================
// zero_shell2: zero the 1-voxel pad shell of TWO padded volumes (y picks).
// ==========================================================================
template <int NCH>
__global__ __launch_bounds__(256) void zero_shell2(_Float16* __restrict__ p0,
                                                   _Float16* __restrict__ p1)
{
    _Float16* p = blockIdx.y ? p1 : p0;
    const int t = blockIdx.x * 256 + threadIdx.x;
    if (t >= NSHELL) return;
    int d, h, w;
    if (t < 33800)      { d = (t < 16900) ? 0 : 129; int r = t % 16900; h = r / 130; w = r % 130; }
    else if (t < 67080) { int r = t - 33800; h = (r < 16640) ? 0 : 129; int q = r % 16640; d = 1 + q / 130; w = q % 130; }
    else                { int r = t - 67080; w = (r < 16384) ? 0 : 129; int q = r % 16384; d = 1 + q / 128; h = 1 + q % 128; }
    const size_t site = (size_t)d * PHW + (size_t)h * PW + w;
    if (NCH == 8) *(f16x8*)(p + site * 8) = (f16x8){};
    else          p[site] = (_Float16)0.f;
}

// ==========================================================================
// cvt_x: planar fp32 (8ch) -> channel-interleaved f16x8, PADDED layout
// ==========================================================================
__global__ __launch_bounds__(256) void cvt_x(const float* __restrict__ x,
                                             _Float16* __restrict__ xi)
{
    const size_t v = (size_t)blockIdx.x * 256 + threadIdx.x;
    const int d = (int)(v >> 14), h = (int)((v >> 7) & 127), w = (int)(v & 127);
    f16x8 o;
#pragma unroll
    for (int c = 0; c < 8; ++c) o[c] = (_Float16)x[(size_t)c * VOL + v];
    *(f16x8*)(xi + ((size_t)(d + 1) * PHW + (size_t)(h + 1) * PW + (w + 1)) * 8) = o;
}

// ==========================================================================
// prepack_all: pack conv weights into exact MFMA A-fragment lane order.
// blocks 0-4 (16x16 layout, OC<=16): entry e=s*64+lane, s=0..6:
//   a[j] = wt[m*216 + j*27 + tap], m=lane&15, tap=s*4+(lane>>4)
// blocks 5-7 (32x32 layout, OC=27): entry e=s*64+lane, s=0..13:
//   a[j] = wt[m*216 + j*27 + tap], m=lane&31, tap=2*s+(lane>>5)
// ==========================================================================
__global__ __launch_bounds__(256) void prepack_all(
    const float* __restrict__ w0, const float* __restrict__ w1,
    const float* __restrict__ w2, const float* __restrict__ w3,
    const float* __restrict__ w4, const float* __restrict__ w5,
    const float* __restrict__ w6, const float* __restrict__ w7,
    _Float16* __restrict__ pb)
{
    const int b = blockIdx.x;
    const float* src; int OC; size_t off;
    switch (b) {
        case 0: src = w0; OC = 8;  off = 0;     break;
        case 1: src = w1; OC = 8;  off = 3584;  break;
        case 2: src = w2; OC = 8;  off = 7168;  break;
        case 3: src = w3; OC = 8;  off = 10752; break;
        case 4: src = w4; OC = 1;  off = 14336; break;
        case 5: src = w5; OC = 27; off = 17920; break;
        case 6: src = w6; OC = 27; off = 25088; break;
        default: src = w7; OC = 27; off = 32256; break;
    }
    const bool big = (b >= 5);
    const int total = big ? 896 : 448;
    for (int e = threadIdx.x; e < total; e += 256) {
        const int s = e >> 6, lane = e & 63;
        const int m   = big ? (lane & 31) : (lane & 15);
        const int tap = big ? (2 * s + (lane >> 5)) : (s * 4 + (lane >> 4));
        f16x8 a = {};
        if (tap < 27 && m < OC) {
#pragma unroll
            for (int j = 0; j < 8; ++j)
                a[j] = (_Float16)src[m * 216 + j * 27 + tap];
        }
        *(f16x8*)(pb + off + (size_t)e * 8) = a;
    }
}

// ==========================================================================
// conv_g: implicit-GEMM 3x3x3 conv via MFMA 16x16x32 f16, OC<=16.
// R8: half-size tile for occupancy — block covers (d, h-pair); tile =
// 3d x 4h x 130w = 1560 sites x 16B = 25.0 KB LDS -> 6 blocks/CU =
// 24 waves/CU (was 16). Wave owns (row hloc, 4 of 8 wsegs). afr loads
// hoisted between stage-issue and ds_write. Math/output bit-identical.
// OM: 0 = padded interleaved 8-ch out, 2 = padded planar 1-ch out.
// ==========================================================================
template <int OC, bool RELU, int OM, typename TO>
__global__ __launch_bounds__(256) void conv_g(const _Float16* __restrict__ in,
                                              const _Float16* __restrict__ apack,
                                              const float* __restrict__ bias,
                                              TO* __restrict__ out)
{
    __shared__ f16x8 lds[1560];            // [dd 0..2][hh 0..3][ww 0..129]

    const int tid  = threadIdx.x;
    const int wid  = tid >> 6;
    const int lane = tid & 63;
    const int n    = lane & 15;
    const int quad = lane >> 4;
    const int hloc = wid & 1;              // row within the h-pair
    const int wsh  = wid >> 1;             // this wave does wsegs wsh*4..wsh*4+3

    const int bid = blockIdx.x;            // 8192 = 8 xcd-slabs x 16 d x 64 h-pairs
    const int idx = bid >> 3;
    const int d   = ((bid & 7) << 4) + (idx & 15);
    const int h0  = (idx >> 4) << 1;
    const int h   = h0 + hloc;

    // ---- stage block tile into LDS (issue loads; afr loads; then writes) --
    f16x8 sv[7];
#pragma unroll
    for (int it = 0; it < 7; ++it) {
        const int sidx = it * 256 + tid;
        if (sidx < 1560) {
            const int dd = sidx / 520;
            const int r  = sidx - dd * 520;
            const int hh = r / 130;
            const int ww = r - hh * 130;
            sv[it] = *(const f16x8*)(in + ((size_t)(d + dd) * PHW + (size_t)(h0 + hh) * PW + ww) * 8);
        }
    }
    f16x8 afr[7];
#pragma unroll
    for (int s = 0; s < 7; ++s)
        afr[s] = *(const f16x8*)(apack + (size_t)(s * 64 + lane) * 8);
#pragma unroll
    for (int it = 0; it < 7; ++it) {
        const int sidx = it * 256 + tid;
        if (sidx < 1560) lds[sidx] = sv[it];
    }
    __syncthreads();

    // LDS site for MFMA s (taps s*4+quad): site = kd*520 + (hloc+kh)*130 + kw,
    // per wseg add wseg*16 + n.
    int vsite[7];
#pragma unroll
    for (int s = 0; s < 7; ++s) {
        int tap = s * 4 + quad;
        if (tap > 26) tap = 26;            // A is zero there; address just valid
        const int kd = tap / 9, kh = (tap % 9) / 3, kw = tap % 3;
        vsite[s] = kd * 520 + (hloc + kh) * 130 + kw;
    }

    float bv[4];
#pragma unroll
    for (int r = 0; r < 4; ++r) {
        const int o = quad * 4 + r;
        bv[r] = (bias != nullptr && o < OC) ? bias[o] : 0.f;
    }

#pragma unroll 2
    for (int i = 0; i < 4; ++i) {
        const int wseg = wsh * 4 + i;
        const int wv = wseg * 16 + n;
        f16x8 bfr[7];
#pragma unroll
        for (int s = 0; s < 7; ++s)
            bfr[s] = lds[vsite[s] + wv];
        f32x4 acc;
        acc[0] = bv[0]; acc[1] = bv[1]; acc[2] = bv[2]; acc[3] = bv[3];
#pragma unroll
        for (int s = 0; s < 7; ++s)
            acc = __builtin_amdgcn_mfma_f32_16x16x32_f16(afr[s], bfr[s], acc, 0, 0, 0);

        if (OM == 0) {
            if (quad < 2) {
                const size_t pvox = (size_t)(d + 1) * PHW + (size_t)(h + 1) * PW + 1 + wv;
                f16x4 o4;
#pragma unroll
                for (int r = 0; r < 4; ++r) {
                    float v = acc[r];
                    if (RELU) v = fmaxf(v, 0.f);
                    o4[r] = (_Float16)v;
                }
                *(f16x4*)((_Float16*)out + pvox * 8 + quad * 4) = o4;
            }
        } else { // OM == 2, OC = 1, padded planar out
            if (quad == 0) {
                const size_t pvox = (size_t)(d + 1) * PHW + (size_t)(h + 1) * PW + 1 + wv;
                float v = acc[0];
                if (RELU) v = fmaxf(v, 0.f);
                stv((TO*)out + pvox, v);
            }
        }
    }
}

// ==========================================================================
// conv27_g: the 8->27 weight conv via MFMA 32x32x16 f16 + L1-normalize.
// R8: half-size tile for occupancy — block covers (d, h-pair); tile =
// 3d x 4h x 130w = 1560 sites = 25.0 KB LDS -> 6 blocks/CU = 24 waves/CU
// (was 4 blocks/16 waves at the 37.9 KB quad tile). Wave owns (row hloc,
// 2 of 4 wsegs). 256 thr, LB(256,4), afr after barrier (R5 pattern —
// R6's LB(512,6) variant spilled). Store: compact 56 B/voxel.
// ==========================================================================
__global__ __launch_bounds__(256, 4) void conv27_g(const _Float16* __restrict__ in,
                                                   const _Float16* __restrict__ apack,
                                                   _Float16* __restrict__ wn)
{
    __shared__ f16x8 lds[1560];            // [dd 0..2][hh 0..3][ww 0..129]

    const int tid  = threadIdx.x;
    const int wid  = tid >> 6;
    const int lane = tid & 63;
    const int col  = lane & 31;
    const int half = lane >> 5;
    const int hloc = wid & 1;              // row within the h-pair
    const int wsh  = wid >> 1;             // this wave does wsegs wsh*2, wsh*2+1

    const int bid = blockIdx.x;            // 8192 = 8 xcd-slabs x 16 d x 64 h-pairs
    const int idx = bid >> 3;
    const int d   = ((bid & 7) << 4) + (idx & 15);
    const int h0  = (idx >> 4) << 1;
    const int h   = h0 + hloc;

    // ---- stage block tile into LDS (issue all loads, then all writes) ----
    f16x8 sv[7];
#pragma unroll
    for (int it = 0; it < 7; ++it) {
        const int sidx = it * 256 + tid;
        if (sidx < 1560) {
            const int dd = sidx / 520;
            const int r  = sidx - dd * 520;
            const int hh = r / 130;
            const int ww = r - hh * 130;
            sv[it] = *(const f16x8*)(in + ((size_t)(d + dd) * PHW + (size_t)(h0 + hh) * PW + ww) * 8);
        }
    }
#pragma unroll
    for (int it = 0; it < 7; ++it) {
        const int sidx = it * 256 + tid;
        if (sidx < 1560) lds[sidx] = sv[it];
    }
    __syncthreads();

    f16x8 afr[14];
#pragma unroll
    for (int s = 0; s < 14; ++s)
        afr[s] = *(const f16x8*)(apack + (size_t)(s * 64 + lane) * 8);

    // LDS site for MFMA s: tap = 2s+half -> (kd,kh,kw);
    // site = kd*520 + (hloc+kh)*130 + kw + col; per wseg add 32.
    int vsite[14];
#pragma unroll
    for (int s = 0; s < 14; ++s) {
        int tap = 2 * s + half;
        if (tap > 26) tap = 26;            // A row zero there
        const int kd = tap / 9, kh = (tap % 9) / 3, kw = tap % 3;
        vsite[s] = kd * 520 + (hloc + kh) * 130 + kw + col;
    }

#pragma unroll 1
    for (int i = 0; i < 2; ++i) {
        const int wseg = wsh * 2 + i;
        const int wb = wseg * 32;
        // rotating 6-deep ds_read prefetch
        f16x8 bfr[6];
#pragma unroll
        for (int s = 0; s < 6; ++s)
            bfr[s] = lds[vsite[s] + wb];
        f32x16 acc = {};
#pragma unroll
        for (int s = 0; s < 14; ++s) {
            acc = __builtin_amdgcn_mfma_f32_32x32x16_f16(afr[s], bfr[s % 6], acc, 0, 0, 0);
            if (s + 6 < 14)
                bfr[s % 6] = lds[vsite[s + 6] + wb];
        }

        // ---- L1 norm over the 27 rows (rows 27-31 are exact zeros) ----
        float p0 = (fabsf(acc[0]) + fabsf(acc[1])) + (fabsf(acc[2]) + fabsf(acc[3]));
        float p1 = (fabsf(acc[4]) + fabsf(acc[5])) + (fabsf(acc[6]) + fabsf(acc[7]));
        float p2 = (fabsf(acc[8]) + fabsf(acc[9])) + (fabsf(acc[10]) + fabsf(acc[11]));
        float p3 = (fabsf(acc[12]) + fabsf(acc[13])) + (fabsf(acc[14]) + fabsf(acc[15]));
        float ssum = (p0 + p1) + (p2 + p3);
        ssum += __shfl_xor(ssum, 32);
        const float inv = __builtin_amdgcn_rcpf(fmaxf(ssum, 1e-12f));

        // ---- scale, pack, store compact (56 B / voxel) ----
        int pk[8];
#pragma unroll
        for (int j = 0; j < 8; ++j) {
            f16x2 t;
            t[0] = (_Float16)(acc[2 * j] * inv);
            t[1] = (_Float16)(acc[2 * j + 1] * inv);
            pk[j] = __builtin_bit_cast(int, t);
        }
        const size_t grp = (size_t)(d * 128 + h) * 4 + wseg;   // vox>>5
        _Float16* gbase = wn + grp * 896;
        if (half == 0) {
            _Float16* dst = gbase + (size_t)col * 16;          // 16B aligned
            int4v v0; v0[0] = pk[0]; v0[1] = pk[1]; v0[2] = pk[2]; v0[3] = pk[3];
            int4v v1; v1[0] = pk[4]; v1[1] = pk[5]; v1[2] = pk[6]; v1[3] = pk[7];
            *(int4v*)dst = v0;
            *(int4v*)(dst + 8) = v1;
        } else {
            _Float16* dst = gbase + 512 + (size_t)col * 12;    // 8B aligned
            int2v a; a[0] = pk[0]; a[1] = pk[1];
            int2v b; b[0] = pk[2]; b[1] = pk[3];
            int2v c; c[0] = pk[4]; c[1] = pk[5];
            *(int2v*)dst = a;
            *(int2v*)(dst + 4) = b;
            *(int2v*)(dst + 8) = c;
        }
    }
}

// weight fetch from compact Wb: tap m -> (h=(m>>2)&1, r=(m&3)+4*(m>>3))
#define WH(m) (((m) >> 2) & 1)
#define WR(m) (((m) & 3) + 4 * ((m) >> 3))

// ==========================================================================
// adapt8: per-voxel 27-tap weights (compact Wb, 56 B/voxel), 8 interleaved
// channels, LDS-staged input tile (R4). R6 (kept): Wb loads issued between
// the stage-load issue and ds_writes (their ~900cy HBM latency drains under
// the staging barrier), and the accumulate is f32x8-vectorized so clang
// emits v_pk_fma_f32 (same fp32 fma numerics, half the issue slots).
// ==========================================================================
__global__ __launch_bounds__(512, 8) void adapt8(const _Float16* __restrict__ in,
                                                 const _Float16* __restrict__ wn,
                                                 _Float16* __restrict__ out)
{
    __shared__ f16x8 lds[2340];            // [dd 0..2][hh 0..5][ww 0..129]

    const int tid = threadIdx.x;
    const int bid = blockIdx.x;            // 4096 = 128 d x 32 h-quads
    const int d  = bid >> 5;
    const int h0 = (bid & 31) << 2;
    const int hl = tid >> 7;               // 0..3
    const int w  = tid & 127;
    const int h  = h0 + hl;

    // ---- stage-load issue ----
    f16x8 sv[5];
#pragma unroll
    for (int it = 0; it < 5; ++it) {
        const int s = it * 512 + tid;
        if (s < 2340) {
            const int dd = s / 780, r = s - dd * 780;
            const int hh = r / 130, ww = r - hh * 130;
            sv[it] = *(const f16x8*)(in + ((size_t)(d + dd) * PHW + (size_t)(h0 + hh) * PW + ww) * 8);
        }
    }

    // ---- Wb loads (HBM) issued now, consumed after the barrier ----
    const size_t vox = (size_t)d * HW + (size_t)h * WW + w;   // unpadded (weights)
    const _Float16* gb = wn + (vox >> 5) * 896;
    const int col = (int)(vox & 31);
    f16x8 wk0[2];
    wk0[0] = *(const f16x8*)(gb + (size_t)col * 16);
    wk0[1] = *(const f16x8*)(gb + (size_t)col * 16 + 8);
    f16x4 wk1[3];
    const _Float16* c1 = gb + 512 + (size_t)col * 12;
    wk1[0] = *(const f16x4*)(c1);
    wk1[1] = *(const f16x4*)(c1 + 4);
    wk1[2] = *(const f16x4*)(c1 + 8);

    // ---- LDS writes (wait only the older stage loads) + barrier ----
#pragma unroll
    for (int it = 0; it < 5; ++it) {
        const int s = it * 512 + tid;
        if (s < 2340) lds[s] = sv[it];
    }
    __syncthreads();

    f32x8v acc = {};
#pragma unroll
    for (int kd = 0; kd < 3; ++kd) {
#pragma unroll
        for (int kh = 0; kh < 3; ++kh) {
            const int rowb = (kd * 6 + hl + kh) * 130 + w;
#pragma unroll
            for (int kw = 0; kw < 3; ++kw) {
                const f16x8 xv = lds[rowb + kw];
                const f32x8v xvf = __builtin_convertvector(xv, f32x8v);
                const int m = kd * 9 + kh * 3 + kw;
                const int r = WR(m);
                const float wvv = WH(m) == 0 ? (float)wk0[r >> 3][r & 7]
                                             : (float)wk1[r >> 2][r & 3];
                acc += xvf * wvv;
            }
        }
    }
    f16x8 o;
#pragma unroll
    for (int c = 0; c < 8; ++c) o[c] = (_Float16)acc[c];
    *(f16x8*)(out + ((size_t)(d + 1) * PHW + (size_t)(h + 1) * PW + (w + 1)) * 8) = o;
}

// ==========================================================================
// adapt1: 1 channel, PADDED planar f16 in; compact Wb weights.
// LDS-staged planar tile (R4); Wb loads hoisted under staging wait (R6).
// PADOUT: padded f16 out, else unpadded float out.
// ==========================================================================
template <bool PADOUT, typename TOUT>
__global__ __launch_bounds__(512) void adapt1(const _Float16* __restrict__ in,
                                              const _Float16* __restrict__ wn,
                                              TOUT* __restrict__ out)
{
    __shared__ _Float16 lds1[2340];        // [dd 0..2][hh 0..5][ww 0..129]

    const int tid = threadIdx.x;
    const int bid = blockIdx.x;            // 4096 = 128 d x 32 h-quads
    const int d  = bid >> 5;
    const int h0 = (bid & 31) << 2;
    const int hl = tid >> 7;               // 0..3
    const int w  = tid & 127;
    const int h  = h0 + hl;

    _Float16 sv[5];
#pragma unroll
    for (int it = 0; it < 5; ++it) {
        const int s = it * 512 + tid;
        if (s < 2340) {
            const int dd = s / 780, r = s - dd * 780;
            const int hh = r / 130, ww = r - hh * 130;
            sv[it] = in[(size_t)(d + dd) * PHW + (size_t)(h0 + hh) * PW + ww];
        }
    }

    const size_t vox = (size_t)d * HW + (size_t)h * WW + w;
    const _Float16* gb = wn + (vox >> 5) * 896;
    const int col = (int)(vox & 31);
    f16x8 wk0[2];
    wk0[0] = *(const f16x8*)(gb + (size_t)col * 16);
    wk0[1] = *(const f16x8*)(gb + (size_t)col * 16 + 8);
    f16x4 wk1[3];
    const _Float16* c1 = gb + 512 + (size_t)col * 12;
    wk1[0] = *(const f16x4*)(c1);
    wk1[1] = *(const f16x4*)(c1 + 4);
    wk1[2] = *(const f16x4*)(c1 + 8);

#pragma unroll
    for (int it = 0; it < 5; ++it) {
        const int s = it * 512 + tid;
        if (s < 2340) lds1[s] = sv[it];
    }
    __syncthreads();

    float acc = 0.f;
#pragma unroll
    for (int kd = 0; kd < 3; ++kd) {
#pragma unroll
        for (int kh = 0; kh < 3; ++kh) {
            const int rowb = (kd * 6 + hl + kh) * 130 + w;
#pragma unroll
            for (int kw = 0; kw < 3; ++kw) {
                const int m = kd * 9 + kh * 3 + kw;
                const int r = WR(m);
                const float wvv = WH(m) == 0 ? (float)wk0[r >> 3][r & 7]
                                             : (float)wk1[r >> 2][r & 3];
                acc += wvv * (float)lds1[rowb + kw];
            }
        }
    }
    if (PADOUT)
        stv(out + (size_t)(d + 1) * PHW + (size_t)(h + 1) * PW + (w + 1), acc);
    else
        stv(out + vox, acc);
}

extern "C" void kernel_launch(void* const* d_in, const int* in_sizes, int n_in,
                              void* d_out, int out_size, void* d_ws, size_t ws_size,
                              hipStream_t stream)
{
    (void)in_sizes; (void)n_in; (void)out_size; (void)ws_size;

    const float* x      = (const float*)d_in[0];
    const float* ac1_w1 = (const float*)d_in[1];
    const float* ac1_b1 = (const float*)d_in[2];
    const float* ac1_w2 = (const float*)d_in[3];
    const float* ac2_w1 = (const float*)d_in[4];
    const float* ac2_b1 = (const float*)d_in[5];
    const float* ac2_w2 = (const float*)d_in[6];
    const float* ac3_w1 = (const float*)d_in[7];
    const float* ac3_b1 = (const float*)d_in[8];
    const float* ac3_w2 = (const float*)d_in[9];
    const float* mid_w  = (const float*)d_in[10];
    const float* mid_b  = (const float*)d_in[11];
    const float* out_w  = (const float*)d_in[12];
    const float* out_b  = (const float*)d_in[13];
    float* outp = (float*)d_out;

    // fp16 scratch: Wb compact 28*V halfs (region reserved 32V) | B1i | B2i
    // | F0 | F1 | packs
    const size_t V = (size_t)VOL;
    _Float16* Wb  = (_Float16*)d_ws;
    _Float16* B1i = Wb + 32 * V;
    _Float16* B2i = B1i + (size_t)8 * PVOL;
    _Float16* F0  = B2i + (size_t)8 * PVOL;
    _Float16* F1  = F0 + (size_t)PVOL;
    _Float16* PB  = F1 + (size_t)PVOL;

    _Float16* pk_ac1w1 = PB + 0;
    _Float16* pk_ac2w1 = PB + 3584;
    _Float16* pk_ac3w1 = PB + 7168;
    _Float16* pk_midw  = PB + 10752;
    _Float16* pk_outw  = PB + 14336;
    _Float16* pk_ac1w2 = PB + 17920;
    _Float16* pk_ac2w2 = PB + 25088;
    _Float16* pk_ac3w2 = PB + 32256;

    const dim3 cgrid(8192), cblk(256);
    const dim3 a8grid(4096), a8blk(512);
    const dim3 a1grid(4096), a1blk(512);
    const dim3 zgrid((NSHELL + 255) / 256, 2), zblk(256);

    // zero only the pad shells (~3.6 MB total), 2 fused dispatches
    zero_shell2<8><<<zgrid, zblk, 0, stream>>>(B1i, B2i);
    zero_shell2<1><<<zgrid, zblk, 0, stream>>>(F0, F1);
    prepack_all<<<8, 256, 0, stream>>>(ac1_w1, ac2_w1, ac3_w1, mid_w, out_w,
                                       ac1_w2, ac2_w2, ac3_w2, PB);
    cvt_x<<<8192, 256, 0, stream>>>(x, B2i);                                   // B2i = x

    // ---- adaptive block 1 (input x = B2i) ----
    conv_g<8, true, 0, _Float16><<<cgrid, cblk, 0, stream>>>(B2i, pk_ac1w1, ac1_b1, B1i);
    conv27_g<<<cgrid, cblk, 0, stream>>>(B1i, pk_ac1w2, Wb);
    adapt8<<<a8grid, a8blk, 0, stream>>>(B2i, Wb, B1i);
    adapt8<<<a8grid, a8blk, 0, stream>>>(B1i, Wb, B2i);
    adapt8<<<a8grid, a8blk, 0, stream>>>(B2i, Wb, B1i);                        // B1i = block1 out
    conv_g<8, false, 0, _Float16><<<cgrid, cblk, 0, stream>>>(B1i, pk_midw, mid_b, B2i); // B2i = mid

    // ---- adaptive block 2 (input mid = B2i) ----
    conv_g<8, true, 0, _Float16><<<cgrid, cblk, 0, stream>>>(B2i, pk_ac2w1, ac2_b1, B1i);
    conv27_g<<<cgrid, cblk, 0, stream>>>(B1i, pk_ac2w2, Wb);
    adapt8<<<a8grid, a8blk, 0, stream>>>(B2i, Wb, B1i);
    adapt8<<<a8grid, a8blk, 0, stream>>>(B1i, Wb, B2i);
    adapt8<<<a8grid, a8blk, 0, stream>>>(B2i, Wb, B1i);                        // B1i = mid2

    // ---- block 3: weights from mid2 = B1i ----
    conv_g<8, true, 0, _Float16><<<cgrid, cblk, 0, stream>>>(B1i, pk_ac3w1, ac3_b1, B2i);
    conv27_g<<<cgrid, cblk, 0, stream>>>(B2i, pk_ac3w2, Wb);
    conv_g<1, false, 2, _Float16><<<cgrid, cblk, 0, stream>>>(B1i, pk_outw, out_b, F0);
    adapt1<true, _Float16><<<a1grid, a1blk, 0, stream>>>(F0, Wb, F1);
    adapt1<true, _Float16><<<a1grid, a1blk, 0, stream>>>(F1, Wb, F0);
    adapt1<false, float><<<a1grid, a1blk, 0, stream>>>(F0, Wb, outp);
}

// Round 9
// 618.142 us; speedup vs baseline: 1.0927x; 1.0927x over previous
//
#include <hip/hip_runtime.h>
#include <hip/hip_fp16.h>
#include <math.h>

#define WW 128
#define HH 128
#define DD 128
#define HW (WW * HH)
#define VOL (WW * HH * DD)
// padded (halo) geometry: 130^3, interior voxel (d,h,w) -> padded (d+1,h+1,w+1)
#define PW 130
#define PHW (130 * 130)
#define PVOL (130 * 130 * 130)
#define NSHELL 99848   // 130^3 - 128^3

typedef _Float16 f16x8 __attribute__((ext_vector_type(8)));
typedef _Float16 f16x4 __attribute__((ext_vector_type(4)));
typedef _Float16 f16x2 __attribute__((ext_vector_type(2)));
typedef float f32x4 __attribute__((ext_vector_type(4)));
typedef float f32x16 __attribute__((ext_vector_type(16)));
typedef int int4v __attribute__((ext_vector_type(4)));
typedef int int2v __attribute__((ext_vector_type(2)));

__device__ __forceinline__ void stv(float* p, float v) { *p = v; }
__device__ __forceinline__ void stv(_Float16* p, float v) { *p = (_Float16)v; }

// Wb compact layout (56 B/voxel, lossless — rows 27..31 of the 32x32 C-tile
// are exact zeros and are dropped):
//   group g = vox>>5 (32 voxels), col = vox&31, group stride = 896 halfs.
//   chunk0 (half0 regs r=0..15, rows (r&3)+8*(r>>2)):  g*896 + col*16, 16 halfs
//   chunk1 (half1 regs r=0..11, rows (r&3)+8*(r>>2)+4): g*896 + 512 + col*12, 12 halfs
// tap m -> (h=(m>>2)&1, r=(m&3)+4*(m>>3)); h==0 -> chunk0[r], h==1 -> chunk1[r].

// ==========================================================================
// zero_shell2: zero the 1-voxel pad shell of TWO padded volumes (y picks).
// ==========================================================================
template <int NCH>
__global__ __launch_bounds__(256) void zero_shell2(_Float16* __restrict__ p0,
                                                   _Float16* __restrict__ p1)
{
    _Float16* p = blockIdx.y ? p1 : p0;
    const int t = blockIdx.x * 256 + threadIdx.x;
    if (t >= NSHELL) return;
    int d, h, w;
    if (t < 33800)      { d = (t < 16900) ? 0 : 129; int r = t % 16900; h = r / 130; w = r % 130; }
    else if (t < 67080) { int r = t - 33800; h = (r < 16640) ? 0 : 129; int q = r % 16640; d = 1 + q / 130; w = q % 130; }
    else                { int r = t - 67080; w = (r < 16384) ? 0 : 129; int q = r % 16384; d = 1 + q / 128; h = 1 + q % 128; }
    const size_t site = (size_t)d * PHW + (size_t)h * PW + w;
    if (NCH == 8) *(f16x8*)(p + site * 8) = (f16x8){};
    else          p[site] = (_Float16)0.f;
}

// ==========================================================================
// cvt_x: planar fp32 (8ch) -> channel-interleaved f16x8, PADDED layout
// ==========================================================================
__global__ __launch_bounds__(256) void cvt_x(const float* __restrict__ x,
                                             _Float16* __restrict__ xi)
{
    const size_t v = (size_t)blockIdx.x * 256 + threadIdx.x;
    const int d = (int)(v >> 14), h = (int)((v >> 7) & 127), w = (int)(v & 127);
    f16x8 o;
#pragma unroll
    for (int c = 0; c < 8; ++c) o[c] = (_Float16)x[(size_t)c * VOL + v];
    *(f16x8*)(xi + ((size_t)(d + 1) * PHW + (size_t)(h + 1) * PW + (w + 1)) * 8) = o;
}

// ==========================================================================
// prepack_all: pack conv weights into exact MFMA A-fragment lane order.
// blocks 0-4 (16x16 layout, OC<=16): entry e=s*64+lane, s=0..6:
//   a[j] = wt[m*216 + j*27 + tap], m=lane&15, tap=s*4+(lane>>4)
// blocks 5-7 (32x32 layout, OC=27): entry e=s*64+lane, s=0..13:
//   a[j] = wt[m*216 + j*27 + tap], m=lane&31, tap=2*s+(lane>>5)
// ==========================================================================
__global__ __launch_bounds__(256) void prepack_all(
    const float* __restrict__ w0, const float* __restrict__ w1,
    const float* __restrict__ w2, const float* __restrict__ w3,
    const float* __restrict__ w4, const float* __restrict__ w5,
    const float* __restrict__ w6, const float* __restrict__ w7,
    _Float16* __restrict__ pb)
{
    const int b = blockIdx.x;
    const float* src; int OC; size_t off;
    switch (b) {
        case 0: src = w0; OC = 8;  off = 0;     break;
        case 1: src = w1; OC = 8;  off = 3584;  break;
        case 2: src = w2; OC = 8;  off = 7168;  break;
        case 3: src = w3; OC = 8;  off = 10752; break;
        case 4: src = w4; OC = 1;  off = 14336; break;
        case 5: src = w5; OC = 27; off = 17920; break;
        case 6: src = w6; OC = 27; off = 25088; break;
        default: src = w7; OC = 27; off = 32256; break;
    }
    const bool big = (b >= 5);
    const int total = big ? 896 : 448;
    for (int e = threadIdx.x; e < total; e += 256) {
        const int s = e >> 6, lane = e & 63;
        const int m   = big ? (lane & 31) : (lane & 15);
        const int tap = big ? (2 * s + (lane >> 5)) : (s * 4 + (lane >> 4));
        f16x8 a = {};
        if (tap < 27 && m < OC) {
#pragma unroll
            for (int j = 0; j < 8; ++j)
                a[j] = (_Float16)src[m * 216 + j * 27 + tap];
        }
        *(f16x8*)(pb + off + (size_t)e * 8) = a;
    }
}

// ==========================================================================
// conv_g: implicit-GEMM 3x3x3 conv via MFMA 16x16x32 f16, OC<=16.
// R9: exact R7 geometry restored (4-row block, 37.4 KB tile) — R8's
// half-tile bought no occupancy (write-drain capped) and added staging
// overhead. afr loads hoisted between stage-issue and ds_write.
// OM: 0 = padded interleaved 8-ch out, 2 = padded planar 1-ch out.
// ==========================================================================
template <int OC, bool RELU, int OM, typename TO>
__global__ __launch_bounds__(256) void conv_g(const _Float16* __restrict__ in,
                                              const _Float16* __restrict__ apack,
                                              const float* __restrict__ bias,
                                              TO* __restrict__ out)
{
    __shared__ f16x8 lds[2340];            // [dd 0..2][hh 0..5][ww 0..129]

    const int tid  = threadIdx.x;
    const int wid  = tid >> 6;
    const int lane = tid & 63;
    const int n    = lane & 15;
    const int quad = lane >> 4;

    const int bid = blockIdx.x;            // 4096 blocks x 4 waves = 16384 (d,h) rows
    const int idx = bid >> 3;
    const int d   = ((bid & 7) << 4) + (idx & 15);
    const int h0  = (idx >> 4) << 2;
    const int h   = h0 + wid;

    // ---- stage block tile into LDS (issue loads; afr loads; then writes) --
    f16x8 sv[10];
#pragma unroll
    for (int it = 0; it < 10; ++it) {
        const int sidx = it * 256 + tid;
        if (sidx < 2340) {
            const int dd = sidx / 780;
            const int r  = sidx - dd * 780;
            const int hh = r / 130;
            const int ww = r - hh * 130;
            sv[it] = *(const f16x8*)(in + ((size_t)(d + dd) * PHW + (size_t)(h0 + hh) * PW + ww) * 8);
        }
    }
    f16x8 afr[7];
#pragma unroll
    for (int s = 0; s < 7; ++s)
        afr[s] = *(const f16x8*)(apack + (size_t)(s * 64 + lane) * 8);
#pragma unroll
    for (int it = 0; it < 10; ++it) {
        const int sidx = it * 256 + tid;
        if (sidx < 2340) lds[sidx] = sv[it];
    }
    __syncthreads();

    // LDS site index for MFMA s (taps s*4+quad) at wseg 0, lane-n excluded:
    // site = (kd*6 + wid+kh)*130 + kw; per wseg add wseg*16 + n.
    int vsite[7];
#pragma unroll
    for (int s = 0; s < 7; ++s) {
        int tap = s * 4 + quad;
        if (tap > 26) tap = 26;            // A is zero there; address just valid
        const int kd = tap / 9, kh = (tap % 9) / 3, kw = tap % 3;
        vsite[s] = (kd * 6 + wid + kh) * 130 + kw;
    }

    float bv[4];
#pragma unroll
    for (int r = 0; r < 4; ++r) {
        const int o = quad * 4 + r;
        bv[r] = (bias != nullptr && o < OC) ? bias[o] : 0.f;
    }

#pragma unroll 2
    for (int wseg = 0; wseg < 8; ++wseg) {
        const int wv = wseg * 16 + n;
        f16x8 bfr[7];
#pragma unroll
        for (int s = 0; s < 7; ++s)
            bfr[s] = lds[vsite[s] + wv];
        f32x4 acc;
        acc[0] = bv[0]; acc[1] = bv[1]; acc[2] = bv[2]; acc[3] = bv[3];
#pragma unroll
        for (int s = 0; s < 7; ++s)
            acc = __builtin_amdgcn_mfma_f32_16x16x32_f16(afr[s], bfr[s], acc, 0, 0, 0);

        if (OM == 0) {
            if (quad < 2) {
                const size_t pvox = (size_t)(d + 1) * PHW + (size_t)(h + 1) * PW + 1 + wv;
                f16x4 o4;
#pragma unroll
                for (int r = 0; r < 4; ++r) {
                    float v = acc[r];
                    if (RELU) v = fmaxf(v, 0.f);
                    o4[r] = (_Float16)v;
                }
                *(f16x4*)((_Float16*)out + pvox * 8 + quad * 4) = o4;
            }
        } else { // OM == 2, OC = 1, padded planar out
            if (quad == 0) {
                const size_t pvox = (size_t)(d + 1) * PHW + (size_t)(h + 1) * PW + 1 + wv;
                float v = acc[0];
                if (RELU) v = fmaxf(v, 0.f);
                stv((TO*)out + pvox, v);
            }
        }
    }
}

// ==========================================================================
// conv27_g: the 8->27 weight conv via MFMA 32x32x16 f16 + L1-normalize.
// R9: exact R7 geometry restored (256 thr, LB(256,4), 37.4 KB quad tile,
// afr after barrier) — the measured-best 41.3 us configuration. R8's
// half-tile regressed (occupancy is write-drain-capped, not LDS-capped);
// R6's LB(512,6) spilled. Store: compact 56 B/voxel.
// ==========================================================================
__global__ __launch_bounds__(256, 4) void conv27_g(const _Float16* __restrict__ in,
                                                   const _Float16* __restrict__ apack,
                                                   _Float16* __restrict__ wn)
{
    __shared__ f16x8 lds[2340];            // [dd 0..2][hh 0..5][ww 0..129]

    const int tid  = threadIdx.x;
    const int wid  = tid >> 6;
    const int lane = tid & 63;
    const int col  = lane & 31;
    const int half = lane >> 5;

    const int bid = blockIdx.x;            // 4096 blocks x 4 waves = 16384 (d,h) rows
    const int idx = bid >> 3;
    const int d   = ((bid & 7) << 4) + (idx & 15);
    const int h0  = (idx >> 4) << 2;       // block base h (4 rows)
    const int h   = h0 + wid;

    // ---- stage block tile into LDS (issue all loads, then all writes) ----
    f16x8 sv[10];
#pragma unroll
    for (int it = 0; it < 10; ++it) {
        const int sidx = it * 256 + tid;
        if (sidx < 2340) {
            const int dd = sidx / 780;
            const int r  = sidx - dd * 780;
            const int hh = r / 130;
            const int ww = r - hh * 130;
            sv[it] = *(const f16x8*)(in + ((size_t)(d + dd) * PHW + (size_t)(h0 + hh) * PW + ww) * 8);
        }
    }
#pragma unroll
    for (int it = 0; it < 10; ++it) {
        const int sidx = it * 256 + tid;
        if (sidx < 2340) lds[sidx] = sv[it];
    }
    __syncthreads();

    f16x8 afr[14];
#pragma unroll
    for (int s = 0; s < 14; ++s)
        afr[s] = *(const f16x8*)(apack + (size_t)(s * 64 + lane) * 8);

    // LDS site index for MFMA s at wseg 0: tap = 2s+half -> (kd,kh,kw);
    // site = (kd*6 + wid+kh)*130 + kw + col; per wseg add 32.
    int vsite[14];
#pragma unroll
    for (int s = 0; s < 14; ++s) {
        int tap = 2 * s + half;
        if (tap > 26) tap = 26;            // A row zero there
        const int kd = tap / 9, kh = (tap % 9) / 3, kw = tap % 3;
        vsite[s] = (kd * 6 + wid + kh) * 130 + kw + col;
    }

#pragma unroll 1
    for (int wseg = 0; wseg < 4; ++wseg) {
        const int wb = wseg * 32;
        // rotating 6-deep ds_read prefetch
        f16x8 bfr[6];
#pragma unroll
        for (int s = 0; s < 6; ++s)
            bfr[s] = lds[vsite[s] + wb];
        f32x16 acc = {};
#pragma unroll
        for (int s = 0; s < 14; ++s) {
            acc = __builtin_amdgcn_mfma_f32_32x32x16_f16(afr[s], bfr[s % 6], acc, 0, 0, 0);
            if (s + 6 < 14)
                bfr[s % 6] = lds[vsite[s + 6] + wb];
        }

        // ---- L1 norm over the 27 rows (rows 27-31 are exact zeros) ----
        float p0 = (fabsf(acc[0]) + fabsf(acc[1])) + (fabsf(acc[2]) + fabsf(acc[3]));
        float p1 = (fabsf(acc[4]) + fabsf(acc[5])) + (fabsf(acc[6]) + fabsf(acc[7]));
        float p2 = (fabsf(acc[8]) + fabsf(acc[9])) + (fabsf(acc[10]) + fabsf(acc[11]));
        float p3 = (fabsf(acc[12]) + fabsf(acc[13])) + (fabsf(acc[14]) + fabsf(acc[15]));
        float ssum = (p0 + p1) + (p2 + p3);
        ssum += __shfl_xor(ssum, 32);
        const float inv = __builtin_amdgcn_rcpf(fmaxf(ssum, 1e-12f));

        // ---- scale, pack, store compact (56 B / voxel) ----
        int pk[8];
#pragma unroll
        for (int i = 0; i < 8; ++i) {
            f16x2 t;
            t[0] = (_Float16)(acc[2 * i] * inv);
            t[1] = (_Float16)(acc[2 * i + 1] * inv);
            pk[i] = __builtin_bit_cast(int, t);
        }
        const size_t grp = (size_t)(d * 128 + h) * 4 + wseg;   // vox>>5
        _Float16* gbase = wn + grp * 896;
        if (half == 0) {
            _Float16* dst = gbase + (size_t)col * 16;          // 16B aligned
            int4v v0; v0[0] = pk[0]; v0[1] = pk[1]; v0[2] = pk[2]; v0[3] = pk[3];
            int4v v1; v1[0] = pk[4]; v1[1] = pk[5]; v1[2] = pk[6]; v1[3] = pk[7];
            *(int4v*)dst = v0;
            *(int4v*)(dst + 8) = v1;
        } else {
            _Float16* dst = gbase + 512 + (size_t)col * 12;    // 8B aligned
            int2v a; a[0] = pk[0]; a[1] = pk[1];
            int2v b; b[0] = pk[2]; b[1] = pk[3];
            int2v c; c[0] = pk[4]; c[1] = pk[5];
            *(int2v*)dst = a;
            *(int2v*)(dst + 4) = b;
            *(int2v*)(dst + 8) = c;
        }
    }
}

// weight fetch from compact Wb: tap m -> (h=(m>>2)&1, r=(m&3)+4*(m>>3))
#define WH(m) (((m) >> 2) & 1)
#define WR(m) (((m) & 3) + 4 * ((m) >> 3))

// ==========================================================================
// adapt8: per-voxel 27-tap weights (compact Wb, 56 B/voxel), 8 interleaved
// channels, LDS-staged input tile (R4) + Wb loads hoisted under the staging
// barrier (R6). R9: inner loop back to SCALAR mixed-precision FMA
// (acc += w * (float)x_f16) so clang emits v_fma_mix_f32 — 8 VALU ops/tap
// vs the R6 f32x8 path's 12 (8 cvt + 4 pk_fma). Numerics bit-identical
// (f16 promoted exactly, fp32 fma either way).
// ==========================================================================
__global__ __launch_bounds__(512, 8) void adapt8(const _Float16* __restrict__ in,
                                                 const _Float16* __restrict__ wn,
                                                 _Float16* __restrict__ out)
{
    __shared__ f16x8 lds[2340];            // [dd 0..2][hh 0..5][ww 0..129]

    const int tid = threadIdx.x;
    const int bid = blockIdx.x;            // 4096 = 128 d x 32 h-quads
    const int d  = bid >> 5;
    const int h0 = (bid & 31) << 2;
    const int hl = tid >> 7;               // 0..3
    const int w  = tid & 127;
    const int h  = h0 + hl;

    // ---- stage-load issue ----
    f16x8 sv[5];
#pragma unroll
    for (int it = 0; it < 5; ++it) {
        const int s = it * 512 + tid;
        if (s < 2340) {
            const int dd = s / 780, r = s - dd * 780;
            const int hh = r / 130, ww = r - hh * 130;
            sv[it] = *(const f16x8*)(in + ((size_t)(d + dd) * PHW + (size_t)(h0 + hh) * PW + ww) * 8);
        }
    }

    // ---- Wb loads (HBM) issued now, consumed after the barrier ----
    const size_t vox = (size_t)d * HW + (size_t)h * WW + w;   // unpadded (weights)
    const _Float16* gb = wn + (vox >> 5) * 896;
    const int col = (int)(vox & 31);
    f16x8 wk0[2];
    wk0[0] = *(const f16x8*)(gb + (size_t)col * 16);
    wk0[1] = *(const f16x8*)(gb + (size_t)col * 16 + 8);
    f16x4 wk1[3];
    const _Float16* c1 = gb + 512 + (size_t)col * 12;
    wk1[0] = *(const f16x4*)(c1);
    wk1[1] = *(const f16x4*)(c1 + 4);
    wk1[2] = *(const f16x4*)(c1 + 8);

    // ---- LDS writes (wait only the older stage loads) + barrier ----
#pragma unroll
    for (int it = 0; it < 5; ++it) {
        const int s = it * 512 + tid;
        if (s < 2340) lds[s] = sv[it];
    }
    __syncthreads();

    float acc[8] = {0.f, 0.f, 0.f, 0.f, 0.f, 0.f, 0.f, 0.f};
#pragma unroll
    for (int kd = 0; kd < 3; ++kd) {
#pragma unroll
        for (int kh = 0; kh < 3; ++kh) {
            const int rowb = (kd * 6 + hl + kh) * 130 + w;
#pragma unroll
            for (int kw = 0; kw < 3; ++kw) {
                const f16x8 xv = lds[rowb + kw];
                const int m = kd * 9 + kh * 3 + kw;
                const int r = WR(m);
                const float wvv = WH(m) == 0 ? (float)wk0[r >> 3][r & 7]
                                             : (float)wk1[r >> 2][r & 3];
#pragma unroll
                for (int c = 0; c < 8; ++c) acc[c] += wvv * (float)xv[c];
            }
        }
    }
    f16x8 o;
#pragma unroll
    for (int c = 0; c < 8; ++c) o[c] = (_Float16)acc[c];
    *(f16x8*)(out + ((size_t)(d + 1) * PHW + (size_t)(h + 1) * PW + (w + 1)) * 8) = o;
}

// ==========================================================================
// adapt1: 1 channel, PADDED planar f16 in; compact Wb weights.
// LDS-staged planar tile (R4); Wb loads hoisted under staging wait (R6).
// PADOUT: padded f16 out, else unpadded float out.
// ==========================================================================
template <bool PADOUT, typename TOUT>
__global__ __launch_bounds__(512) void adapt1(const _Float16* __restrict__ in,
                                              const _Float16* __restrict__ wn,
                                              TOUT* __restrict__ out)
{
    __shared__ _Float16 lds1[2340];        // [dd 0..2][hh 0..5][ww 0..129]

    const int tid = threadIdx.x;
    const int bid = blockIdx.x;            // 4096 = 128 d x 32 h-quads
    const int d  = bid >> 5;
    const int h0 = (bid & 31) << 2;
    const int hl = tid >> 7;               // 0..3
    const int w  = tid & 127;
    const int h  = h0 + hl;

    _Float16 sv[5];
#pragma unroll
    for (int it = 0; it < 5; ++it) {
        const int s = it * 512 + tid;
        if (s < 2340) {
            const int dd = s / 780, r = s - dd * 780;
            const int hh = r / 130, ww = r - hh * 130;
            sv[it] = in[(size_t)(d + dd) * PHW + (size_t)(h0 + hh) * PW + ww];
        }
    }

    const size_t vox = (size_t)d * HW + (size_t)h * WW + w;
    const _Float16* gb = wn + (vox >> 5) * 896;
    const int col = (int)(vox & 31);
    f16x8 wk0[2];
    wk0[0] = *(const f16x8*)(gb + (size_t)col * 16);
    wk0[1] = *(const f16x8*)(gb + (size_t)col * 16 + 8);
    f16x4 wk1[3];
    const _Float16* c1 = gb + 512 + (size_t)col * 12;
    wk1[0] = *(const f16x4*)(c1);
    wk1[1] = *(const f16x4*)(c1 + 4);
    wk1[2] = *(const f16x4*)(c1 + 8);

#pragma unroll
    for (int it = 0; it < 5; ++it) {
        const int s = it * 512 + tid;
        if (s < 2340) lds1[s] = sv[it];
    }
    __syncthreads();

    float acc = 0.f;
#pragma unroll
    for (int kd = 0; kd < 3; ++kd) {
#pragma unroll
        for (int kh = 0; kh < 3; ++kh) {
            const int rowb = (kd * 6 + hl + kh) * 130 + w;
#pragma unroll
            for (int kw = 0; kw < 3; ++kw) {
                const int m = kd * 9 + kh * 3 + kw;
                const int r = WR(m);
                const float wvv = WH(m) == 0 ? (float)wk0[r >> 3][r & 7]
                                             : (float)wk1[r >> 2][r & 3];
                acc += wvv * (float)lds1[rowb + kw];
            }
        }
    }
    if (PADOUT)
        stv(out + (size_t)(d + 1) * PHW + (size_t)(h + 1) * PW + (w + 1), acc);
    else
        stv(out + vox, acc);
}

extern "C" void kernel_launch(void* const* d_in, const int* in_sizes, int n_in,
                              void* d_out, int out_size, void* d_ws, size_t ws_size,
                              hipStream_t stream)
{
    (void)in_sizes; (void)n_in; (void)out_size; (void)ws_size;

    const float* x      = (const float*)d_in[0];
    const float* ac1_w1 = (const float*)d_in[1];
    const float* ac1_b1 = (const float*)d_in[2];
    const float* ac1_w2 = (const float*)d_in[3];
    const float* ac2_w1 = (const float*)d_in[4];
    const float* ac2_b1 = (const float*)d_in[5];
    const float* ac2_w2 = (const float*)d_in[6];
    const float* ac3_w1 = (const float*)d_in[7];
    const float* ac3_b1 = (const float*)d_in[8];
    const float* ac3_w2 = (const float*)d_in[9];
    const float* mid_w  = (const float*)d_in[10];
    const float* mid_b  = (const float*)d_in[11];
    const float* out_w  = (const float*)d_in[12];
    const float* out_b  = (const float*)d_in[13];
    float* outp = (float*)d_out;

    // fp16 scratch: Wb compact 28*V halfs (region reserved 32V) | B1i | B2i
    // | F0 | F1 | packs
    const size_t V = (size_t)VOL;
    _Float16* Wb  = (_Float16*)d_ws;
    _Float16* B1i = Wb + 32 * V;
    _Float16* B2i = B1i + (size_t)8 * PVOL;
    _Float16* F0  = B2i + (size_t)8 * PVOL;
    _Float16* F1  = F0 + (size_t)PVOL;
    _Float16* PB  = F1 + (size_t)PVOL;

    _Float16* pk_ac1w1 = PB + 0;
    _Float16* pk_ac2w1 = PB + 3584;
    _Float16* pk_ac3w1 = PB + 7168;
    _Float16* pk_midw  = PB + 10752;
    _Float16* pk_outw  = PB + 14336;
    _Float16* pk_ac1w2 = PB + 17920;
    _Float16* pk_ac2w2 = PB + 25088;
    _Float16* pk_ac3w2 = PB + 32256;

    const dim3 cgrid(4096), cblk(256);
    const dim3 a8grid(4096), a8blk(512);
    const dim3 a1grid(4096), a1blk(512);
    const dim3 zgrid((NSHELL + 255) / 256, 2), zblk(256);

    // zero only the pad shells (~3.6 MB total), 2 fused dispatches
    zero_shell2<8><<<zgrid, zblk, 0, stream>>>(B1i, B2i);
    zero_shell2<1><<<zgrid, zblk, 0, stream>>>(F0, F1);
    prepack_all<<<8, 256, 0, stream>>>(ac1_w1, ac2_w1, ac3_w1, mid_w, out_w,
                                       ac1_w2, ac2_w2, ac3_w2, PB);
    cvt_x<<<8192, 256, 0, stream>>>(x, B2i);                                   // B2i = x

    // ---- adaptive block 1 (input x = B2i) ----
    conv_g<8, true, 0, _Float16><<<cgrid, cblk, 0, stream>>>(B2i, pk_ac1w1, ac1_b1, B1i);
    conv27_g<<<cgrid, cblk, 0, stream>>>(B1i, pk_ac1w2, Wb);
    adapt8<<<a8grid, a8blk, 0, stream>>>(B2i, Wb, B1i);
    adapt8<<<a8grid, a8blk, 0, stream>>>(B1i, Wb, B2i);
    adapt8<<<a8grid, a8blk, 0, stream>>>(B2i, Wb, B1i);                        // B1i = block1 out
    conv_g<8, false, 0, _Float16><<<cgrid, cblk, 0, stream>>>(B1i, pk_midw, mid_b, B2i); // B2i = mid

    // ---- adaptive block 2 (input mid = B2i) ----
    conv_g<8, true, 0, _Float16><<<cgrid, cblk, 0, stream>>>(B2i, pk_ac2w1, ac2_b1, B1i);
    conv27_g<<<cgrid, cblk, 0, stream>>>(B1i, pk_ac2w2, Wb);
    adapt8<<<a8grid, a8blk, 0, stream>>>(B2i, Wb, B1i);
    adapt8<<<a8grid, a8blk, 0, stream>>>(B1i, Wb, B2i);
    adapt8<<<a8grid, a8blk, 0, stream>>>(B2i, Wb, B1i);                        // B1i = mid2

    // ---- block 3: weights from mid2 = B1i ----
    conv_g<8, true, 0, _Float16><<<cgrid, cblk, 0, stream>>>(B1i, pk_ac3w1, ac3_b1, B2i);
    conv27_g<<<cgrid, cblk, 0, stream>>>(B2i, pk_ac3w2, Wb);
    conv_g<1, false, 2, _Float16><<<cgrid, cblk, 0, stream>>>(B1i, pk_outw, out_b, F0);
    adapt1<true, _Float16><<<a1grid, a1blk, 0, stream>>>(F0, Wb, F1);
    adapt1<true, _Float16><<<a1grid, a1blk, 0, stream>>>(F1, Wb, F0);
    adapt1<false, float><<<a1grid, a1blk, 0, stream>>>(F0, Wb, outp);
}